// Round 8
// baseline (152.991 us; speedup 1.0000x reference)
//
#include <hip/hip_runtime.h>
#include <math.h>

#define SEQ  2048
#define ROWS 4096
#define D0   512
#define D1   64

typedef short bf8 __attribute__((ext_vector_type(8)));   // 8 bf16 = 4 VGPRs
typedef float f4  __attribute__((ext_vector_type(4)));   // MFMA acc

// fp32 -> bf16 (RNE) and hi/lo split
__device__ __forceinline__ unsigned short f2bf(float f) {
    unsigned u = __float_as_uint(f);
    return (unsigned short)((u + 0x7fffu + ((u >> 16) & 1u)) >> 16);
}
__device__ __forceinline__ float bf2f(unsigned short u) {
    return __uint_as_float((unsigned)u << 16);
}
__device__ __forceinline__ void hilo(float f, unsigned short& h, unsigned short& l) {
    h = f2bf(f);
    float fh = bf2f(h);
    l = f2bf(f - fh);
}
__device__ __forceinline__ void cv4h(unsigned short* dh, int idx, float4 v) {
    ushort4 hv;
    hv.x = f2bf(v.x); hv.y = f2bf(v.y); hv.z = f2bf(v.z); hv.w = f2bf(v.w);
    *(ushort4*)(dh + idx) = hv;
}

// async global->LDS 16B (dest = wave-uniform base + lane*16)
__device__ __forceinline__ void async16(const void* g, void* l) {
    __builtin_amdgcn_global_load_lds(
        (const __attribute__((address_space(1))) unsigned int*)g,
        (__attribute__((address_space(3))) unsigned int*)l, 16, 0, 0);
}

// ---------------------------------------------------------------------------
// convk: weights -> bf16 hi planes ([M2;R2], [W3;R3], W1) + A1/A3 transpose.
// 256 blocks: [0,192) conversions (2048 els each), [192,256) transposes.
// ---------------------------------------------------------------------------
__global__ __launch_bounds__(256) void convk(
        const float* __restrict__ W1, const float* __restrict__ M2,
        const float* __restrict__ R2, const float* __restrict__ W3,
        const float* __restrict__ R3, const float* __restrict__ A1,
        const float* __restrict__ A3,
        unsigned short* __restrict__ W1h,
        unsigned short* __restrict__ C2h,
        unsigned short* __restrict__ C3h,
        float* __restrict__ A1T, float* __restrict__ A3T) {
    int c = blockIdx.x, tid = threadIdx.x;
    if (c < 192) {
        const float* src; unsigned short* dh; int off;
        if      (c < 128) { src = W1; dh = W1h;         off = c; }
        else if (c < 144) { src = M2; dh = C2h;         off = c - 128; }
        else if (c < 160) { src = R2; dh = C2h + 32768; off = c - 144; }
        else if (c < 176) { src = W3; dh = C3h;         off = c - 160; }
        else              { src = R3; dh = C3h + 32768; off = c - 176; }
        int base = off * 2048 + tid * 4;
        cv4h(dh, base,        *(const float4*)(src + base));
        cv4h(dh, base + 1024, *(const float4*)(src + base + 1024));
    } else {
        int g0 = ((c - 192) * 256 + tid) * 2;   // 0..32766
#pragma unroll
        for (int e = g0; e < g0 + 2; ++e) {
            int i = e >> 6, j = e & 63;         // A is 512 x 64
            A1T[j * 512 + i] = A1[e];
            A3T[j * 512 + i] = A3[e];
        }
    }
}

// ---------------------------------------------------------------------------
// g1f: fused layer 1. Block = 16 rows x full N=512, K=512.
// A-frags: direct global fp32 loads of x + in-register bf16 cvt (hi only).
// W: per-K-tile 512x64 bf16 slab staged via async16 into 64 KB LDS (swizzled).
// Epilogue: same LDS re-aliased as fp32 C-tile (16 x 516); per-row LN +
// rank-1 RN + fp32 x residual -> h1 bf16 hi/lo planes.
// ---------------------------------------------------------------------------
__global__ __launch_bounds__(256) void g1f(
        const float* __restrict__ x, const unsigned short* __restrict__ W1h,
        const float* __restrict__ g1, const float* __restrict__ b1,
        const float* __restrict__ B1, const float* __restrict__ A1T,
        unsigned short* __restrict__ h1h, unsigned short* __restrict__ h1l) {
    __shared__ __align__(16) unsigned short smem[32768];     // 64 KB
    unsigned short* wS = smem;
    float (*cS)[516] = (float(*)[516])smem;                  // epilogue alias
    const int tid = threadIdx.x;
    const int w   = tid >> 6;
    const int ln  = tid & 63;
    const int lm  = ln & 15;
    const int lq  = ln >> 4;
    const int bm  = blockIdx.x * 16;

    f4 acc[8] = {};    // wave w: n-cols [w*128 + it*16, +16)

    for (int kt = 0; kt < 8; ++kt) {
        __syncthreads();
        // A frags: global fp32 + cvt (independent of LDS; overlaps staging)
        bf8 af[2];
#pragma unroll
        for (int kk = 0; kk < 2; ++kk) {
            const float* xp = x + (size_t)(bm + lm) * 512 + kt * 64 + kk * 32 + lq * 8;
            float4 u0 = *(const float4*)xp;
            float4 u1 = *(const float4*)(xp + 4);
            bf8 a;
            a[0] = (short)f2bf(u0.x); a[1] = (short)f2bf(u0.y);
            a[2] = (short)f2bf(u0.z); a[3] = (short)f2bf(u0.w);
            a[4] = (short)f2bf(u1.x); a[5] = (short)f2bf(u1.y);
            a[6] = (short)f2bf(u1.z); a[7] = (short)f2bf(u1.w);
            af[kk] = a;
        }
        // stage W slab: 512 rows x 8 chunks, swizzled on global side
#pragma unroll
        for (int i = 0; i < 16; ++i) {
            int slot = i * 256 + tid;
            int row  = slot >> 3;
            int cg   = (slot & 7) ^ (row & 7);
            async16(W1h + (size_t)row * 512 + kt * 64 + cg * 8, wS + slot * 8);
        }
        __syncthreads();
#pragma unroll
        for (int it = 0; it < 8; ++it) {
#pragma unroll
            for (int kk = 0; kk < 2; ++kk) {
                int rb = w * 128 + it * 16 + lm;
                bf8 bh = *(const bf8*)(wS + rb * 64 + (((kk * 4 + lq) ^ (rb & 7)) * 8));
                acc[it] = __builtin_amdgcn_mfma_f32_16x16x32_bf16(af[kk], bh, acc[it], 0, 0, 0);
            }
        }
    }
    __syncthreads();    // wS reads done; re-alias as cS
    // C/D layout (verified): col = lane&15, row = quad*4 + reg
#pragma unroll
    for (int it = 0; it < 8; ++it)
#pragma unroll
        for (int r = 0; r < 4; ++r)
            cS[lq * 4 + r][w * 128 + it * 16 + lm] = acc[it][r];
    __syncthreads();

    // epilogue: wave w handles local rows w*4 .. w*4+3
    for (int q = 0; q < 4; ++q) {
        const int row = w * 4 + q;
        const int gr  = bm + row;
        const int c   = ln * 8;
        float4 y0 = *(const float4*)&cS[row][c];
        float4 y1 = *(const float4*)&cS[row][c + 4];
        float sum = y0.x + y0.y + y0.z + y0.w + y1.x + y1.y + y1.z + y1.w;
        float ssq = y0.x*y0.x + y0.y*y0.y + y0.z*y0.z + y0.w*y0.w
                  + y1.x*y1.x + y1.y*y1.y + y1.z*y1.z + y1.w*y1.w;
#pragma unroll
        for (int m = 1; m < 64; m <<= 1) {
            sum += __shfl_xor(sum, m, 64);
            ssq += __shfl_xor(ssq, m, 64);
        }
        float mean = sum * (1.0f / 512.0f);
        float var  = ssq * (1.0f / 512.0f) - mean * mean;
        float rstd = rsqrtf(var + 1e-5f);
        float4 g0 = *(const float4*)(g1 + c), g1v = *(const float4*)(g1 + c + 4);
        float4 e0 = *(const float4*)(b1 + c), e1  = *(const float4*)(b1 + c + 4);
        float4 n0, n1;
        n0.x = (y0.x - mean) * rstd * g0.x  + e0.x;
        n0.y = (y0.y - mean) * rstd * g0.y  + e0.y;
        n0.z = (y0.z - mean) * rstd * g0.z  + e0.z;
        n0.w = (y0.w - mean) * rstd * g0.w  + e0.w;
        n1.x = (y1.x - mean) * rstd * g1v.x + e1.x;
        n1.y = (y1.y - mean) * rstd * g1v.y + e1.y;
        n1.z = (y1.z - mean) * rstd * g1v.z + e1.z;
        n1.w = (y1.w - mean) * rstd * g1v.w + e1.w;
        const int jm = gr & 63;
        const float* bb = B1 + jm * D0 + c;
        float4 b0 = *(const float4*)bb, b1v = *(const float4*)(bb + 4);
        float p = n0.x*b0.x + n0.y*b0.y + n0.z*b0.z + n0.w*b0.w
                + n1.x*b1v.x + n1.y*b1v.y + n1.z*b1v.z + n1.w*b1v.w;
#pragma unroll
        for (int m = 1; m < 64; m <<= 1) p += __shfl_xor(p, m, 64);
        const float* av = A1T + jm * D0 + c;
        float4 a0 = *(const float4*)av, a1 = *(const float4*)(av + 4);
        const float* rs = x + (size_t)gr * D0 + c;
        float4 r0 = *(const float4*)rs, r1 = *(const float4*)(rs + 4);
        float4 v0, v1;
        v0.x = p*a0.x + r0.x; v0.y = p*a0.y + r0.y; v0.z = p*a0.z + r0.z; v0.w = p*a0.w + r0.w;
        v1.x = p*a1.x + r1.x; v1.y = p*a1.y + r1.y; v1.z = p*a1.z + r1.z; v1.w = p*a1.w + r1.w;
        ushort4 h0, l0, h1v, l1;
        hilo(v0.x, h0.x, l0.x); hilo(v0.y, h0.y, l0.y);
        hilo(v0.z, h0.z, l0.z); hilo(v0.w, h0.w, l0.w);
        hilo(v1.x, h1v.x, l1.x); hilo(v1.y, h1v.y, l1.y);
        hilo(v1.z, h1v.z, l1.z); hilo(v1.w, h1v.w, l1.w);
        *(ushort4*)(h1h + (size_t)gr * D0 + c)     = h0;
        *(ushort4*)(h1l + (size_t)gr * D0 + c)     = l0;
        *(ushort4*)(h1h + (size_t)gr * D0 + c + 4) = h1v;
        *(ushort4*)(h1l + (size_t)gr * D0 + c + 4) = l1;
    }
}

// ---------------------------------------------------------------------------
// gemm128t: 128x64-tile MFMA GEMM (as R7, passed). OM==1: bf16 split-K
// partials. A = bf16 hi+lo planes, W = bf16 hi plane. XOR-swizzled LDS.
// ---------------------------------------------------------------------------
template<bool ALO, int OM>
__global__ __launch_bounds__(256, 4) void gemm128t(
        const unsigned short* __restrict__ Ah, const unsigned short* __restrict__ Al,
        const unsigned short* __restrict__ Wh,
        float* __restrict__ Cf, unsigned short* __restrict__ Cb,
        int M, int N, int K, int Ks) {
    __shared__ __align__(16) unsigned short aH[8192];
    __shared__ __align__(16) unsigned short aL[ALO ? 8192 : 16];
    __shared__ __align__(16) unsigned short wH[4096];
    const int tid = threadIdx.x;
    const int wv  = tid >> 6;
    const int ln  = tid & 63;
    const int lm  = ln & 15;
    const int lq  = ln >> 4;
    const int bm  = blockIdx.y * 128;
    const int bn  = blockIdx.x * 64;
    const int k0  = blockIdx.z * Ks;

    f4 acc[2][4] = {};

    for (int kt = 0; kt < Ks; kt += 64) {
        const int kg = k0 + kt;
        __syncthreads();
#pragma unroll
        for (int i = 0; i < 4; ++i) {
            int slot = i * 256 + wv * 64 + ln;
            int row  = slot >> 3;
            int ch   = (slot & 7) ^ (row & 7);
            size_t go = (size_t)(bm + row) * K + kg + ch * 8;
            async16(Ah + go, aH + slot * 8);
            if constexpr (ALO) async16(Al + go, aL + slot * 8);
        }
#pragma unroll
        for (int i = 0; i < 2; ++i) {
            int slot = i * 256 + wv * 64 + ln;
            int row  = slot >> 3;
            int ch   = (slot & 7) ^ (row & 7);
            size_t go = (size_t)(bn + row) * K + kg + ch * 8;
            async16(Wh + go, wH + slot * 8);
        }
        __syncthreads();

#pragma unroll
        for (int kk = 0; kk < 2; ++kk) {
            const int ck = kk * 4 + lq;
            bf8 a_h[2], a_l[2], b_h[4];
#pragma unroll
            for (int t = 0; t < 2; ++t) {
                int r = wv * 32 + t * 16 + lm;
                a_h[t] = *(const bf8*)(aH + r * 64 + ((ck ^ (r & 7)) * 8));
                if constexpr (ALO)
                    a_l[t] = *(const bf8*)(aL + r * 64 + ((ck ^ (r & 7)) * 8));
            }
#pragma unroll
            for (int u = 0; u < 4; ++u) {
                int rb = u * 16 + lm;
                b_h[u] = *(const bf8*)(wH + rb * 64 + ((ck ^ (rb & 7)) * 8));
            }
#pragma unroll
            for (int t = 0; t < 2; ++t)
#pragma unroll
                for (int u = 0; u < 4; ++u) {
                    acc[t][u] = __builtin_amdgcn_mfma_f32_16x16x32_bf16(a_h[t], b_h[u], acc[t][u], 0, 0, 0);
                    if constexpr (ALO)
                        acc[t][u] = __builtin_amdgcn_mfma_f32_16x16x32_bf16(a_l[t], b_h[u], acc[t][u], 0, 0, 0);
                }
        }
    }

#pragma unroll
    for (int t = 0; t < 2; ++t)
#pragma unroll
        for (int u = 0; u < 4; ++u) {
            int row = bm + wv * 32 + t * 16 + lq * 4;
            int col = bn + u * 16 + lm;
#pragma unroll
            for (int r = 0; r < 4; ++r) {
                float v = acc[t][u][r];
                if constexpr (OM == 0)
                    Cf[(size_t)blockIdx.z * M * N + (size_t)(row + r) * N + col] = v;
                else
                    Cb[(size_t)blockIdx.z * M * N + (size_t)(row + r) * N + col] = f2bf(v);
            }
        }
}

// ---------------------------------------------------------------------------
// lnt: sum 4 bf16 split-K partials of C2; LN y-half -> t; residual -> rsum.
// ---------------------------------------------------------------------------
#define C2S 524288
__global__ __launch_bounds__(256) void lnt(
        const unsigned short* __restrict__ C2b, const float* __restrict__ g2,
        const float* __restrict__ b2,
        float* __restrict__ t, float* __restrict__ rsum) {
    const int r = blockIdx.x * 4 + (threadIdx.x >> 6);   // 0..4095
    const int j = threadIdx.x & 63;
    size_t base = (size_t)r * 128 + j;
    float v = 0.f, rv = 0.f;
#pragma unroll
    for (int z = 0; z < 4; ++z) {
        v  += bf2f(C2b[(size_t)z * C2S + base]);
        rv += bf2f(C2b[(size_t)z * C2S + base + 64]);
    }
    float sum = v, ssq = v * v;
#pragma unroll
    for (int m = 1; m < 64; m <<= 1) {
        sum += __shfl_xor(sum, m, 64);
        ssq += __shfl_xor(ssq, m, 64);
    }
    float mean = sum * (1.0f / 64.0f);
    float var  = ssq * (1.0f / 64.0f) - mean * mean;
    float rstd = rsqrtf(var + 1e-5f);
    t[r * 64 + j]    = (v - mean) * rstd * g2[j] + b2[j];
    rsum[r * 64 + j] = rv;
}

// ---------------------------------------------------------------------------
// tsk2: Chebyshev-recurrence TS layer (verified R5-R7).
// ---------------------------------------------------------------------------
__global__ __launch_bounds__(256) void tsk2(
        const float* __restrict__ t, const float* __restrict__ rsum,
        const float* __restrict__ P,
        unsigned short* __restrict__ Hh, unsigned short* __restrict__ Hl) {
    const int bid = blockIdx.x;
    const int i   = bid >> 3;
    const int sg  = bid & 7;
    const int w   = threadIdx.x >> 6;
    const int ln  = threadIdx.x & 63;       // j
    const int s0  = sg * 256 + w * 64;
    const int idx = i * 64 + ln;
    const float* pp = P + idx * 8;
    const float sf0 = (float)s0;

    float k2c[8], ca[8], cb[8];
#pragma unroll
    for (int g = 0; g < 8; ++g) {
        float pf   = (float)(idx * 8 + g + 2);
        float invp = __builtin_amdgcn_rcpf(pf);
        k2c[g] = 2.0f * __builtin_amdgcn_cosf(invp);     // 2*cos(2*pi/p)
        float q0 = floorf(sf0 * invp);
        float r0 = fmaf(-q0, pf, sf0);
        float f0 = r0 * invp; f0 -= floorf(f0);
        float c0 = __builtin_amdgcn_cosf(f0);
        float sf1 = sf0 + 1.0f;
        float q1 = floorf(sf1 * invp);
        float r1 = fmaf(-q1, pf, sf1);
        float f1 = r1 * invp; f1 -= floorf(f1);
        float c1 = __builtin_amdgcn_cosf(f1);
        float Pv = pp[g];
        ca[g] = Pv * c0;
        cb[g] = Pv * c1;
    }

    const int tb = s0 * 64 + ln;
    float t0c = t[tb], t1c = t[131072 + tb];
    float res0 = 0.f, res1 = 0.f;

    for (int st = 0; st < 64; st += 2) {
        float t0n  = t[tb + (st + 1) * 64];
        float t1n  = t[131072 + tb + (st + 1) * 64];
        float ws = ((ca[0] + ca[1]) + (ca[2] + ca[3]))
                 + ((ca[4] + ca[5]) + (ca[6] + ca[7]));
#pragma unroll
        for (int g = 0; g < 8; ++g) ca[g] = fmaf(k2c[g], cb[g], -ca[g]);
        float v0 = ws * t0c, v1 = ws * t1c;
#pragma unroll
        for (int m = 1; m < 64; m <<= 1) {
            v0 += __shfl_xor(v0, m, 64);
            v1 += __shfl_xor(v1, m, 64);
        }
        res0 = (ln == st) ? v0 : res0;
        res1 = (ln == st) ? v1 : res1;
        float t0n2 = t[tb + (st + 2) * 64];
        float t1n2 = t[131072 + tb + (st + 2) * 64];
        float ws2 = ((cb[0] + cb[1]) + (cb[2] + cb[3]))
                  + ((cb[4] + cb[5]) + (cb[6] + cb[7]));
#pragma unroll
        for (int g = 0; g < 8; ++g) cb[g] = fmaf(k2c[g], ca[g], -cb[g]);
        float v0b = ws2 * t0n, v1b = ws2 * t1n;
#pragma unroll
        for (int m = 1; m < 64; m <<= 1) {
            v0b += __shfl_xor(v0b, m, 64);
            v1b += __shfl_xor(v1b, m, 64);
        }
        res0 = (ln == st + 1) ? v0b : res0;
        res1 = (ln == st + 1) ? v1b : res1;
        t0c = t0n2; t1c = t1n2;
    }

    const int s = s0 + ln;
    {
        float v = res0 + rsum[(size_t)s * 64 + i];
        unsigned short h, l; hilo(v, h, l);
        Hh[(size_t)s * 64 + i] = h; Hl[(size_t)s * 64 + i] = l;
        float v1e = res1 + rsum[(size_t)(SEQ + s) * 64 + i];
        hilo(v1e, h, l);
        Hh[(size_t)(SEQ + s) * 64 + i] = h; Hl[(size_t)(SEQ + s) * 64 + i] = l;
    }
}

// ---------------------------------------------------------------------------
// g3f: fused layer 3. Block = 16 rows x full N=1024 ([W3;R3]), K=64.
// A-frags: direct global bf16 hi+lo loads of h2 (16B, lane-resident rows).
// W: two 512-row chunks staged into the 64 KB LDS slab per chunk.
// Epilogue: LDS re-aliased as fp32 C-tile 16x1024 (y | residual); per-row
// LN + rank-1 + residual -> out fp32.
// ---------------------------------------------------------------------------
__global__ __launch_bounds__(256) void g3f(
        const unsigned short* __restrict__ h2h, const unsigned short* __restrict__ h2l,
        const unsigned short* __restrict__ Wc3h,
        const float* __restrict__ g3, const float* __restrict__ b3,
        const float* __restrict__ B3, const float* __restrict__ A3T,
        float* __restrict__ out) {
    __shared__ __align__(16) unsigned short smem[32768];     // 64 KB
    unsigned short* wS = smem;
    float (*cS)[1024] = (float(*)[1024])smem;                // epilogue alias
    const int tid = threadIdx.x;
    const int w   = tid >> 6;
    const int ln  = tid & 63;
    const int lm  = ln & 15;
    const int lq  = ln >> 4;
    const int bm  = blockIdx.x * 16;

    // A frags (K=64): direct 16B global loads, hi + lo
    bf8 ah[2], al[2];
#pragma unroll
    for (int kk = 0; kk < 2; ++kk) {
        size_t ao = (size_t)(bm + lm) * 64 + kk * 32 + lq * 8;
        ah[kk] = *(const bf8*)(h2h + ao);
        al[kk] = *(const bf8*)(h2l + ao);
    }

    f4 acc[2][8] = {};   // [chunk][it]; wave w cols ch*512 + w*128 + it*16

#pragma unroll
    for (int ch = 0; ch < 2; ++ch) {
        __syncthreads();
#pragma unroll
        for (int i = 0; i < 16; ++i) {
            int slot = i * 256 + tid;
            int row  = slot >> 3;
            int cg   = (slot & 7) ^ (row & 7);
            async16(Wc3h + (size_t)(ch * 512 + row) * 64 + cg * 8, wS + slot * 8);
        }
        __syncthreads();
#pragma unroll
        for (int it = 0; it < 8; ++it) {
#pragma unroll
            for (int kk = 0; kk < 2; ++kk) {
                int rb = w * 128 + it * 16 + lm;
                bf8 bh = *(const bf8*)(wS + rb * 64 + (((kk * 4 + lq) ^ (rb & 7)) * 8));
                acc[ch][it] = __builtin_amdgcn_mfma_f32_16x16x32_bf16(ah[kk], bh, acc[ch][it], 0, 0, 0);
                acc[ch][it] = __builtin_amdgcn_mfma_f32_16x16x32_bf16(al[kk], bh, acc[ch][it], 0, 0, 0);
            }
        }
    }
    __syncthreads();    // wS reads done; re-alias as cS
#pragma unroll
    for (int ch = 0; ch < 2; ++ch)
#pragma unroll
        for (int it = 0; it < 8; ++it)
#pragma unroll
            for (int r = 0; r < 4; ++r)
                cS[lq * 4 + r][ch * 512 + w * 128 + it * 16 + lm] = acc[ch][it][r];
    __syncthreads();

    for (int q = 0; q < 4; ++q) {
        const int row = w * 4 + q;
        const int gr  = bm + row;
        const int c   = ln * 8;
        float4 y0 = *(const float4*)&cS[row][c];
        float4 y1 = *(const float4*)&cS[row][c + 4];
        float sum = y0.x + y0.y + y0.z + y0.w + y1.x + y1.y + y1.z + y1.w;
        float ssq = y0.x*y0.x + y0.y*y0.y + y0.z*y0.z + y0.w*y0.w
                  + y1.x*y1.x + y1.y*y1.y + y1.z*y1.z + y1.w*y1.w;
#pragma unroll
        for (int m = 1; m < 64; m <<= 1) {
            sum += __shfl_xor(sum, m, 64);
            ssq += __shfl_xor(ssq, m, 64);
        }
        float mean = sum * (1.0f / 512.0f);
        float var  = ssq * (1.0f / 512.0f) - mean * mean;
        float rstd = rsqrtf(var + 1e-5f);
        float4 g0 = *(const float4*)(g3 + c), g1v = *(const float4*)(g3 + c + 4);
        float4 e0 = *(const float4*)(b3 + c), e1  = *(const float4*)(b3 + c + 4);
        float4 n0, n1;
        n0.x = (y0.x - mean) * rstd * g0.x  + e0.x;
        n0.y = (y0.y - mean) * rstd * g0.y  + e0.y;
        n0.z = (y0.z - mean) * rstd * g0.z  + e0.z;
        n0.w = (y0.w - mean) * rstd * g0.w  + e0.w;
        n1.x = (y1.x - mean) * rstd * g1v.x + e1.x;
        n1.y = (y1.y - mean) * rstd * g1v.y + e1.y;
        n1.z = (y1.z - mean) * rstd * g1v.z + e1.z;
        n1.w = (y1.w - mean) * rstd * g1v.w + e1.w;
        const int jm = gr & 63;
        const float* bb = B3 + jm * D0 + c;
        float4 b0 = *(const float4*)bb, b1v = *(const float4*)(bb + 4);
        float p = n0.x*b0.x + n0.y*b0.y + n0.z*b0.z + n0.w*b0.w
                + n1.x*b1v.x + n1.y*b1v.y + n1.z*b1v.z + n1.w*b1v.w;
#pragma unroll
        for (int m = 1; m < 64; m <<= 1) p += __shfl_xor(p, m, 64);
        const float* av = A3T + jm * D0 + c;
        float4 a0 = *(const float4*)av, a1 = *(const float4*)(av + 4);
        float4 r0, r1;
        r0 = *(const float4*)&cS[row][512 + c];
        r1 = *(const float4*)&cS[row][512 + c + 4];
        float4 v0, v1;
        v0.x = p*a0.x + r0.x; v0.y = p*a0.y + r0.y; v0.z = p*a0.z + r0.z; v0.w = p*a0.w + r0.w;
        v1.x = p*a1.x + r1.x; v1.y = p*a1.y + r1.y; v1.z = p*a1.z + r1.z; v1.w = p*a1.w + r1.w;
        *(float4*)(out + (size_t)gr * D0 + c)     = v0;
        *(float4*)(out + (size_t)gr * D0 + c + 4) = v1;
    }
}

// ---------------------------------------------------------------------------
extern "C" void kernel_launch(void* const* d_in, const int* in_sizes, int n_in,
                              void* d_out, int out_size, void* d_ws, size_t ws_size,
                              hipStream_t stream) {
    const float* x  = (const float*)d_in[0];
    const float* W1 = (const float*)d_in[1];
    const float* g1 = (const float*)d_in[2];
    const float* b1 = (const float*)d_in[3];
    const float* A1 = (const float*)d_in[4];
    const float* B1 = (const float*)d_in[5];
    const float* M2 = (const float*)d_in[6];
    const float* g2 = (const float*)d_in[7];
    const float* b2 = (const float*)d_in[8];
    const float* P2 = (const float*)d_in[9];
    const float* R2 = (const float*)d_in[10];
    const float* W3 = (const float*)d_in[11];
    const float* g3 = (const float*)d_in[12];
    const float* b3 = (const float*)d_in[13];
    const float* A3 = (const float*)d_in[14];
    const float* B3 = (const float*)d_in[15];
    const float* R3 = (const float*)d_in[16];

    float* ws = (float*)d_ws;
    float* t    = ws;                  // 262,144
    float* rsum = ws + 262144;         // 262,144 (must follow t: overrun pad)
    float* A1T  = ws + 524288;         // 32,768
    float* A3T  = ws + 557056;         // 32,768
    unsigned short* us = (unsigned short*)(ws + 589824);
    unsigned short* h1h  = us;                  // 2,097,152
    unsigned short* h1l  = us + 2097152;        // 2,097,152
    unsigned short* W1h  = us + 4194304;        // 262,144
    unsigned short* Wc2h = us + 4456448;        // 65,536 (128 x 512)
    unsigned short* Wc3h = us + 4521984;        // 65,536 (1024 x 64)
    unsigned short* h2h  = us + 4587520;        // 262,144
    unsigned short* h2l  = us + 4849664;        // 262,144
    unsigned short* C2b  = us + 5111808;        // 4 x 524,288 bf16 partials

    dim3 blk(256);

    // 0) weights -> bf16 + A transposes
    convk<<<256, blk, 0, stream>>>(W1, M2, R2, W3, R3, A1, A3,
                                   W1h, Wc2h, Wc3h, A1T, A3T);

    // 1) fused layer 1: x -> h1 hi/lo planes
    g1f<<<256, blk, 0, stream>>>(x, W1h, g1, b1, B1, A1T, h1h, h1l);

    // 2) C2b = h1 @ [M2;R2]^T (split-K=4, bf16 partials); t/rsum; TS -> h2
    gemm128t<true, 1><<<dim3(2, 32, 4), blk, 0, stream>>>(
        h1h, h1l, Wc2h, nullptr, C2b, ROWS, 128, 512, 128);
    lnt<<<1024, blk, 0, stream>>>(C2b, g2, b2, t, rsum);
    tsk2<<<512, blk, 0, stream>>>(t, rsum, P2, h2h, h2l);

    // 3) fused layer 3: h2 -> out fp32
    g3f<<<256, blk, 0, stream>>>(h2h, h2l, Wc3h, g3, b3, B3, A3T,
                                 (float*)d_out);
}